// Round 7
// baseline (332.904 us; speedup 1.0000x reference)
//
#include <hip/hip_runtime.h>

// ---------------- problem constants ----------------
// B=4096 batch, D=2048 dim, H=3 hidden layers, O=1 output
#define BB 4096
#define DD 2048

typedef float f32x4 __attribute__((ext_vector_type(4)));
typedef __bf16 bf16x8 __attribute__((ext_vector_type(8)));

typedef __attribute__((address_space(1))) unsigned int gl_u32;
typedef __attribute__((address_space(3))) unsigned int lds_u32;

#define GLOAD_LDS16(gptr, sptr) \
  __builtin_amdgcn_global_load_lds((gl_u32*)(void*)(gptr), (lds_u32*)(sptr), 16, 0, 0)

__device__ __forceinline__ unsigned short f2bf(float f) {
  unsigned int u = __float_as_uint(f);
  u += 0x7fffu + ((u >> 16) & 1u);   // round-to-nearest-even
  return (unsigned short)(u >> 16);
}

// fast softplus: v_exp_f32 + v_log_f32 (quarter-rate HW ops).
__device__ __forceinline__ float sp(float x) {
  float t = __expf(-fabsf(x));
  return fmaxf(x, 0.0f) + __logf(1.0f + t);
}

__device__ __forceinline__ void prep_w_vec4(
    const float* __restrict__ mu, const float* __restrict__ rho,
    const float* __restrict__ eps, unsigned short* __restrict__ Wh,
    long long i)
{
  float4 m = ((const float4*)mu)[i];
  float4 r = ((const float4*)rho)[i];
  float4 e = ((const float4*)eps)[i];
  ushort4 o;
  o.x = f2bf(m.x + e.x * sp(r.x));
  o.y = f2bf(m.y + e.y * sp(r.y));
  o.z = f2bf(m.z + e.z * sp(r.z));
  o.w = f2bf(m.w + e.w * sp(r.w));
  ((ushort4*)Wh)[i] = o;
}

__device__ __forceinline__ void prep_f32_vec4(
    const float* __restrict__ mu, const float* __restrict__ rho,
    const float* __restrict__ eps, float* __restrict__ out, long long i)
{
  float4 m = ((const float4*)mu)[i];
  float4 r = ((const float4*)rho)[i];
  float4 e = ((const float4*)eps)[i];
  float4 o;
  o.x = m.x + e.x * sp(r.x);
  o.y = m.y + e.y * sp(r.y);
  o.z = m.z + e.z * sp(r.z);
  o.w = m.w + e.w * sp(r.w);
  ((float4*)out)[i] = o;
}

// ---------------- prep0: only what gemm1 needs: W0->bf16, x->bf16, b0 ----
// Also zeroes the last-block counter IN-GRAPH (ws is re-poisoned to 0xAA
// before every timed launch; prep0 runs first every replay).
__global__ __launch_bounds__(512) void prep0_kernel(
    const float* __restrict__ x,
    const float* __restrict__ wmuh, const float* __restrict__ wrhoh,
    const float* __restrict__ bmuh, const float* __restrict__ brhoh,
    const float* __restrict__ epswh, const float* __restrict__ epsbh,
    unsigned short* __restrict__ Wh, unsigned short* __restrict__ Xb,
    float* __restrict__ bh, unsigned int* __restrict__ counter)
{
  const int b = blockIdx.x;
  const int t = threadIdx.x;
  if (b < 512) {
    long long base = (long long)b * 2048 + t;
    #pragma unroll
    for (int j = 0; j < 4; ++j)
      prep_w_vec4(wmuh, wrhoh, epswh, Wh, base + j * 512);
    return;
  }
  if (b < 1536) {
    long long base = (long long)(b - 512) * 2048 + t;
    #pragma unroll
    for (int j = 0; j < 4; ++j) {
      float4 v = ((const float4*)x)[base + j * 512];
      ushort4 o;
      o.x = f2bf(v.x); o.y = f2bf(v.y); o.z = f2bf(v.z); o.w = f2bf(v.w);
      ((ushort4*)Xb)[base + j * 512] = o;
    }
    return;
  }
  // b == 1536: bias layer 0 (512 vec4) + counter init
  prep_f32_vec4(bmuh, brhoh, epsbh, bh, t);
  if (t == 0) *counter = 0u;
}

// ---------------- GEMM geometry (R6: m97-style 4x4 acc) ----------------
// C = relu(A @ W^T + bias). A: 4096x2048 bf16 row-major, W: 2048x2048 bf16.
// 128x128 tile, BK=64, 256 threads = 4 waves (2x2), wave tile 64x64 via 4x4
// grid of 16x16x32 MFMA: 16 MFMA per 8 ds_read_b128 = 32 FLOP/LDS-byte
// (R5's 64x32 waves were 21.8 — LDS-read throughput was the binder).
// global_load_lds(16B) staging, XOR swizzle folded into the global address
// (R5 measured SQ_LDS_BANK_CONFLICT = 0 with this swizzle).
// XCD-aware remap: patch p=id&7 covers an 8x8 tile patch.
// d_out rule (R5): overwrite-only, single producer block in one dispatch.
#define NGEMM 512

struct GemmCoords { int m0, n0, mw, nw; int srow[4], sgc[4]; };

__device__ __forceinline__ GemmCoords gemm_coords(int id, int t) {
  GemmCoords g;
  const int w = t >> 6;                      // 0..3
  const int p = id & 7;
  const int i4 = id >> 3;
  const int mt = (p & 3) * 8 + (i4 & 7);     // 0..31
  const int nt = (p >> 2) * 8 + (i4 >> 3);   // 0..15
  g.m0 = mt * 128;
  g.n0 = nt * 128;
  g.mw = (w >> 1) * 64;
  g.nw = (w & 1) * 64;
  #pragma unroll
  for (int i = 0; i < 4; ++i) {              // 1024 16B chunks per matrix
    int c = i * 256 + t;
    g.srow[i] = c >> 3;                      // tile row 0..127
    g.sgc[i] = (c & 7) ^ (g.srow[i] & 7);    // swizzled 16B-chunk col 0..7
  }
  return g;
}

__device__ __forceinline__ void gemm_mainloop(
    const unsigned short* __restrict__ A,
    const unsigned short* __restrict__ W,
    unsigned short* sA, unsigned short* sB,
    const GemmCoords& gc, int t, f32x4 (&acc)[4][4])
{
  const int K = DD;
  const int l = t & 63;
  const int lq = l >> 4;
  const int lr = l & 15;
  for (int kt = 0; kt < K; kt += 64) {
    #pragma unroll
    for (int i = 0; i < 4; ++i) {
      int c = i * 256 + t;
      const unsigned short* ga = A + (size_t)(gc.m0 + gc.srow[i]) * K + kt + gc.sgc[i] * 8;
      GLOAD_LDS16(ga, &sA[c * 8]);
      const unsigned short* gb = W + (size_t)(gc.n0 + gc.srow[i]) * K + kt + gc.sgc[i] * 8;
      GLOAD_LDS16(gb, &sB[c * 8]);
    }
    __syncthreads();

    #pragma unroll
    for (int s = 0; s < 2; ++s) {
      bf16x8 af[4], bfr[4];
      int g = s * 4 + lq;
      #pragma unroll
      for (int i = 0; i < 4; ++i) {
        int ra = gc.mw + i * 16 + lr;
        af[i] = *(const bf16x8*)&sA[ra * 64 + (g ^ (ra & 7)) * 8];
        int rb = gc.nw + i * 16 + lr;
        bfr[i] = *(const bf16x8*)&sB[rb * 64 + (g ^ (rb & 7)) * 8];
      }
      #pragma unroll
      for (int i = 0; i < 4; ++i)
        #pragma unroll
        for (int j = 0; j < 4; ++j)
          acc[i][j] = __builtin_amdgcn_mfma_f32_16x16x32_bf16(af[i], bfr[j], acc[i][j], 0, 0, 0);
    }
    __syncthreads();
  }
}

__device__ __forceinline__ void gemm_epilogue_store(
    const GemmCoords& gc, int t, f32x4 (&acc)[4][4],
    const float* __restrict__ bias, unsigned short* __restrict__ C)
{
  const int N = DD;
  const int l = t & 63;
  const int lq = l >> 4;
  const int lr = l & 15;
  #pragma unroll
  for (int j = 0; j < 4; ++j) {
    int n = gc.n0 + gc.nw + j * 16 + lr;
    float bv = bias[n];
    #pragma unroll
    for (int i = 0; i < 4; ++i) {
      int mbase = gc.m0 + gc.mw + i * 16 + lq * 4;
      #pragma unroll
      for (int r = 0; r < 4; ++r) {
        float v = fmaxf(acc[i][j][r] + bv, 0.0f);
        C[(size_t)(mbase + r) * N + n] = f2bf(v);
      }
    }
  }
}

// gemm1 + fused prep tail (W1/W2/b1/b2/wo)
__global__ __launch_bounds__(256, 2) void gemm_relu_fused_kernel(
    const unsigned short* __restrict__ A,
    const unsigned short* __restrict__ W,
    const float* __restrict__ bias,
    unsigned short* __restrict__ C,
    const float* __restrict__ wmuh, const float* __restrict__ wrhoh,
    const float* __restrict__ bmuh, const float* __restrict__ brhoh,
    const float* __restrict__ wmuo, const float* __restrict__ wrhoo,
    const float* __restrict__ epswh, const float* __restrict__ epsbh,
    const float* __restrict__ epswo,
    unsigned short* __restrict__ Wh, float* __restrict__ bh,
    float* __restrict__ wo)
{
  __shared__ unsigned short sA[128 * 64];
  __shared__ unsigned short sB[128 * 64];

  const int id = blockIdx.x;
  const int t = threadIdx.x;   // 0..255

  if (id >= NGEMM) {
    const int pb = id - NGEMM;
    if (pb < 1024) {
      // W1,W2: vec4 idx 1048576..3145727, 2048/block, 8/thread
      long long base = 1048576LL + (long long)pb * 2048 + t;
      #pragma unroll
      for (int j = 0; j < 8; ++j)
        prep_w_vec4(wmuh, wrhoh, epswh, Wh, base + j * 256);
      return;
    }
    // smalls: b1,b2 (bh vec4 512..1535), wo (512 vec4)
    #pragma unroll
    for (int j = 0; j < 4; ++j)
      prep_f32_vec4(bmuh, brhoh, epsbh, bh, 512 + j * 256 + t);
    #pragma unroll
    for (int j = 0; j < 2; ++j)
      prep_f32_vec4(wmuo, wrhoo, epswo, wo, j * 256 + t);
    return;
  }

  GemmCoords gc = gemm_coords(id, t);
  f32x4 acc[4][4] = {};
  gemm_mainloop(A, W, sA, sB, gc, t, acc);
  gemm_epilogue_store(gc, t, acc, bias, C);
}

// plain gemm (layer 2)
__global__ __launch_bounds__(256, 2) void gemm_relu_kernel(
    const unsigned short* __restrict__ A,
    const unsigned short* __restrict__ W,
    const float* __restrict__ bias,
    unsigned short* __restrict__ C)
{
  __shared__ unsigned short sA[128 * 64];
  __shared__ unsigned short sB[128 * 64];
  const int t = threadIdx.x;
  GemmCoords gc = gemm_coords(blockIdx.x, t);
  f32x4 acc[4][4] = {};
  gemm_mainloop(A, W, sA, sB, gc, t, acc);
  gemm_epilogue_store(gc, t, acc, bias, C);
}

// layer 3 + dot with wo + last-block final reduce (writes d_out once).
// Pbuf[nt*4096 + m] = sum over this block's 128 cols of relu(acc+b2)*wo.
__global__ __launch_bounds__(256, 2) void gemm_relu_dot_kernel(
    const unsigned short* __restrict__ A,
    const unsigned short* __restrict__ W,
    const float* __restrict__ bias,
    const float* __restrict__ wo,
    float* __restrict__ Pbuf,
    unsigned int* __restrict__ counter,
    const float* __restrict__ bmuo, const float* __restrict__ brhoo,
    const float* __restrict__ epsbo,
    float* __restrict__ out)
{
  __shared__ unsigned short sA[128 * 64];
  __shared__ unsigned short sB[128 * 64];
  __shared__ int s_last;
  const int t = threadIdx.x;

  GemmCoords gc = gemm_coords(blockIdx.x, t);
  f32x4 acc[4][4] = {};
  gemm_mainloop(A, W, sA, sB, gc, t, acc);

  const int l = t & 63;
  const int w = t >> 6;
  const int lq = l >> 4;
  const int lr = l & 15;

  float bv[4], wv[4];
  #pragma unroll
  for (int j = 0; j < 4; ++j) {
    int n = gc.n0 + gc.nw + j * 16 + lr;
    bv[j] = bias[n];
    wv[j] = wo[n];
  }
  float partial[4][4];
  #pragma unroll
  for (int i = 0; i < 4; ++i)
    #pragma unroll
    for (int r = 0; r < 4; ++r) {
      float v = 0.0f;
      #pragma unroll
      for (int j = 0; j < 4; ++j)
        v += fmaxf(acc[i][j][r] + bv[j], 0.0f) * wv[j];
      partial[i][r] = v;
    }

  // butterfly over lr (lane bits 0..3, stays within quad)
  #pragma unroll
  for (int d = 1; d <= 8; d <<= 1)
    #pragma unroll
    for (int i = 0; i < 4; ++i)
      #pragma unroll
      for (int r = 0; r < 4; ++r)
        partial[i][r] += __shfl_xor(partial[i][r], d, 64);

  // cross-wave reduce via LDS (reuse sA; mainloop ended with __syncthreads)
  float* sRed = (float*)sA;   // [128 rows][2 col-halves]
  if (lr == 0) {
    #pragma unroll
    for (int i = 0; i < 4; ++i)
      #pragma unroll
      for (int r = 0; r < 4; ++r) {
        int row = gc.mw + i * 16 + lq * 4 + r;   // 0..127 in tile
        sRed[row * 2 + (w & 1)] = partial[i][r];
      }
  }
  __syncthreads();
  if (t < 128) {
    float s = sRed[t * 2 + 0] + sRed[t * 2 + 1];
    int nt = gc.n0 >> 7;
    Pbuf[nt * BB + gc.m0 + t] = s;
  }

  // ---- last-block reduction (canonical threadfence pattern) ----
  __threadfence();          // make this block's Pbuf stores device-visible
  __syncthreads();
  if (t == 0) {
    unsigned int old = atomicAdd(counter, 1u);
    s_last = (old == NGEMM - 1) ? 1 : 0;
  }
  __syncthreads();
  if (s_last) {
    __threadfence();        // acquire: see all other blocks' Pbuf stores
    float bo = bmuo[0] + epsbo[0] * sp(brhoo[0]);
    #pragma unroll
    for (int j = 0; j < 16; ++j) {
      int m = j * 256 + t;
      float s = bo;
      #pragma unroll
      for (int nt = 0; nt < 16; ++nt)
        s += Pbuf[nt * BB + m];
      out[m] = s;           // overwrite-only, single producer
    }
  }
}

// ---------------- launch ----------------
extern "C" void kernel_launch(void* const* d_in, const int* in_sizes, int n_in,
                              void* d_out, int out_size, void* d_ws, size_t ws_size,
                              hipStream_t stream) {
  const float* x     = (const float*)d_in[0];
  const float* wmuh  = (const float*)d_in[1];
  const float* wrhoh = (const float*)d_in[2];
  const float* bmuh  = (const float*)d_in[3];
  const float* brhoh = (const float*)d_in[4];
  const float* wmuo  = (const float*)d_in[5];
  const float* wrhoo = (const float*)d_in[6];
  const float* bmuo  = (const float*)d_in[7];
  const float* brhoo = (const float*)d_in[8];
  const float* epswh = (const float*)d_in[9];
  const float* epsbh = (const float*)d_in[10];
  const float* epswo = (const float*)d_in[11];
  const float* epsbo = (const float*)d_in[12];

  char* ws = (char*)d_ws;
  unsigned short* Wh = (unsigned short*)(ws);                       // 25165824 B
  unsigned short* Xb = (unsigned short*)(ws + 25165824);            // 16777216 B
  unsigned short* Ha = (unsigned short*)(ws + 25165824 + 16777216);
  unsigned short* Hb = (unsigned short*)(ws + 25165824 + 2 * 16777216);
  float* bh   = (float*)(ws + 25165824 + 3 * 16777216);             // 24576 B
  float* wo   = (float*)(ws + 25165824 + 3 * 16777216 + 24576);     // 8192 B
  float* Pbuf = (float*)(ws + 25165824 + 3 * 16777216 + 24576 + 8192); // 262144 B
  unsigned int* counter = (unsigned int*)(ws + 25165824 + 3 * 16777216 + 24576 + 8192 + 262144);

  prep0_kernel<<<1537, 512, 0, stream>>>(
      x, wmuh, wrhoh, bmuh, brhoh, epswh, epsbh, Wh, Xb, bh, counter);

  gemm_relu_fused_kernel<<<NGEMM + 1025, 256, 0, stream>>>(
      Xb, Wh, bh, Ha,
      wmuh, wrhoh, bmuh, brhoh, wmuo, wrhoo,
      epswh, epsbh, epswo, Wh, bh, wo);

  gemm_relu_kernel<<<NGEMM, 256, 0, stream>>>(Ha, Wh + 1 * 4194304, bh + DD, Hb);

  gemm_relu_dot_kernel<<<NGEMM, 256, 0, stream>>>(
      Hb, Wh + 2 * 4194304, bh + 2 * DD, wo, Pbuf,
      counter, bmuo, brhoo, epsbo, (float*)d_out);
}